// Round 7
// baseline (3274.126 us; speedup 1.0000x reference)
//
#include <hip/hip_runtime.h>
#include <hip/hip_bf16.h>

typedef unsigned short u16;
typedef unsigned int u32;
typedef __bf16 bf16x8 __attribute__((ext_vector_type(8)));
typedef _Float16 f16x8 __attribute__((ext_vector_type(8)));
typedef float f32x4 __attribute__((ext_vector_type(4)));

#define B_ 64
#define T_ 256
#define I_ 256
#define H_ 512
#define O_ 256
#define D_ 16
#define NWG 64
#define CM_SCALE 64.0f
#define CM_INV   0.015625f

__device__ __forceinline__ bf16x8 ld_bf8(const u16* p){
  uint4 u = *(const uint4*)p;
  return __builtin_bit_cast(bf16x8, u);
}

// ---------- elementwise prep: f32 -> bf16 hi/lo split (afferent GEMM inputs) ----------
__global__ __launch_bounds__(256) void k_split(const float* __restrict__ src,
    u16* __restrict__ hi, u16* __restrict__ lo, int n){
  int i = blockIdx.x*256 + threadIdx.x;
  if (i >= n) return;
  float v = src[i];
  __bf16 h = (__bf16)v;
  __bf16 l = (__bf16)(v - (float)h);
  hi[i] = __builtin_bit_cast(u16, h);
  lo[i] = __builtin_bit_cast(u16, l);
}

// ---------- cm[d][ho][i] = relu(0.125 - |d - clip(tau,1,16)|/64) * lateral, f16 scaled x64 ----------
__global__ __launch_bounds__(256) void k_prep_cm(const float* __restrict__ tau,
    const float* __restrict__ lat, _Float16* __restrict__ cmf){
  int idx = blockIdx.x*256 + threadIdx.x;
  if (idx >= D_*H_*H_) return;
  int d = idx / (H_*H_) + 1;      // 1..16
  int r = idx % (H_*H_);
  float tc = fminf(fmaxf(tau[r], 1.0f), (float)D_);
  float cr = fmaxf(0.0f, 0.125f - fabsf((float)d - tc) * 0.015625f);
  cmf[idx] = (_Float16)(cr * lat[r] * CM_SCALE);
}

// ---------- afferent: acc[t][b][ho] = x[b][t][:] . wa[ho][:] + ba[ho] (3-MFMA bf16 split) ----------
__global__ __launch_bounds__(256) void k_aff(const u16* __restrict__ xhi,
    const u16* __restrict__ xlo, const u16* __restrict__ wahi,
    const u16* __restrict__ walo, const float* __restrict__ ba,
    float* __restrict__ acc, float* __restrict__ aff_last){
  int g = blockIdx.x;            // 1024 blocks
  int mg = g >> 2, ng = g & 3;   // 64-row m-group, 128-col n-group
  int tid = threadIdx.x;
  int w = tid >> 6, l = tid & 63;
  int lr = l & 15, lk8 = (l >> 4) * 8;
  f32x4 accr[4][2];
  #pragma unroll
  for (int a=0;a<4;++a){ accr[a][0]=(f32x4){0.f,0.f,0.f,0.f}; accr[a][1]=(f32x4){0.f,0.f,0.f,0.f}; }
  #pragma unroll 1
  for (int kk = 0; kk < 8; ++kk){
    int i = kk*32 + lk8;
    bf16x8 ahi[4], alo[4];
    #pragma unroll
    for (int mt = 0; mt < 4; ++mt){
      int r = mg*64 + mt*16 + lr;      // r = t*64 + b
      int t = r >> 6, b = r & 63;
      size_t off = ((size_t)b*T_ + t)*I_ + i;
      ahi[mt] = ld_bf8(xhi + off);
      alo[mt] = ld_bf8(xlo + off);
    }
    #pragma unroll
    for (int nj = 0; nj < 2; ++nj){
      int ho = ng*128 + w*32 + nj*16 + lr;
      bf16x8 bhi = ld_bf8(wahi + (size_t)ho*I_ + i);
      bf16x8 blo = ld_bf8(walo + (size_t)ho*I_ + i);
      #pragma unroll
      for (int mt = 0; mt < 4; ++mt){
        accr[mt][nj] = __builtin_amdgcn_mfma_f32_16x16x32_bf16(ahi[mt], bhi, accr[mt][nj],0,0,0);
        accr[mt][nj] = __builtin_amdgcn_mfma_f32_16x16x32_bf16(alo[mt], bhi, accr[mt][nj],0,0,0);
        accr[mt][nj] = __builtin_amdgcn_mfma_f32_16x16x32_bf16(ahi[mt], blo, accr[mt][nj],0,0,0);
      }
    }
  }
  #pragma unroll
  for (int mt=0; mt<4; ++mt)
    #pragma unroll
    for (int nj=0; nj<2; ++nj){
      int ho = ng*128 + w*32 + nj*16 + lr;
      float bias = ba[ho];
      #pragma unroll
      for (int r2=0;r2<4;++r2){
        int r = mg*64 + mt*16 + (l>>4)*4 + r2;   // r = t*64 + b
        float v = accr[mt][nj][r2] + bias;
        acc[(size_t)r*H_ + ho] = v;
        if ((r >> 6) == T_-1) aff_last[(size_t)(r & 63)*H_ + ho] = v;
      }
    }
}

// ---------- persistent recurrence: gather, delay-pair merged producers ----------
// WG g: n = g&3 (128-col out block), p = g>>2 (0..15): half = p&1 (i0), jp = p>>1,
// delays d0 = 2*jp+1, d1 = 2*jp+2. Step t: h(t-d0),h(t-d1) slabs [64x256] -> tanh ->
// LDS; MFMA K=512 (B0 from LDS, B1 from VGPR frags); ONE atomicAdd per element
// covering both delays (16 producers/element instead of 32).
__global__ __launch_bounds__(256,1) void k_rec(const _Float16* __restrict__ cmf,
    float* __restrict__ acc, int* __restrict__ ctr){
  __shared__ char lds[131072];   // [0,64K): cm[d0] slice swz; [64K,96K): A0; [96K,128K): A1
  char* ldsB0 = lds;
  char* ldsA0 = lds + 65536;
  char* ldsA1 = lds + 98304;
  const int g = blockIdx.x;
  const int n = g & 3;
  const int p = g >> 2;
  const int half = p & 1;
  const int jp = p >> 1;
  const int d0 = 2*jp + 1;
  const int d1 = 2*jp + 2;
  const int i0 = half * 256;
  const int tid = threadIdx.x;
  const int w = tid >> 6, l = tid & 63;
  const int lr = l & 15, lkg = l >> 4;

  // stage cm[d0] slice into LDS (once) — identical to R6
  for (int it = tid; it < 4096; it += 256){
    int ho = it >> 5;
    int c8 = (it & 31) * 8;
    f16x8 v = *(const f16x8*)(cmf + (((size_t)(d0-1)*H_ + n*128 + ho)*H_ + i0 + c8));
    int byte = (ho*512 + c8*2) ^ ((ho & 7) << 4);
    *(f16x8*)(ldsB0 + byte) = v;
  }
  // cm[d1] slice into VGPR B-fragments: wave w cols nj -> ho = n*128+w*32+nj*16+lr,
  // frag kk: k = i0 + kk*32 + lkg*8 (+e). Same mapping as the LDS-B read in R6.
  f16x8 bfr1[2][8];
  #pragma unroll
  for (int nj = 0; nj < 2; ++nj){
    const _Float16* bp = cmf + (((size_t)(d1-1)*H_ + n*128 + w*32 + nj*16 + lr)*H_ + i0);
    #pragma unroll
    for (int kk = 0; kk < 8; ++kk)
      bfr1[nj][kk] = *(const f16x8*)(bp + kk*32 + lkg*8);
  }
  __syncthreads();

  const int arow = tid >> 2;           // pack: batch row this thread handles
  const int q    = tid & 3;
  const int cofs = q + ((arow & 1) << 2);  // conflict-free write slots (R6)

  for (int t = 0; t < T_; ++t){
    if (t >= d0){
      // ---- wait: acc[t-d0] complete (monotone => acc[t-d1] also, when t>=d1) ----
      if (tid == 0){
        while (__hip_atomic_load(ctr + (t-d0), __ATOMIC_RELAXED, __HIP_MEMORY_SCOPE_AGENT) < NWG)
          __builtin_amdgcn_s_sleep(1);
      }
      __syncthreads();

      const bool do1 = (t >= d1);
      // ---- load both slabs (LLC-coherent), tanh, pack f16 into ldsA0/ldsA1 ----
      {
        f32x4 a0[16], a1[16];
        const float* s0 = acc + ((size_t)(t-d0)*B_ + arow)*H_ + i0;
        #pragma unroll
        for (int j = 0; j < 8; ++j){
          int c = (4*j + cofs) & 31;
          asm volatile("global_load_dwordx4 %0, %1, off sc0 sc1"
                       : "=v"(a0[2*j])   : "v"(s0 + c*8));
          asm volatile("global_load_dwordx4 %0, %1, off sc0 sc1"
                       : "=v"(a0[2*j+1]) : "v"(s0 + c*8 + 4));
        }
        if (do1){
          const float* s1 = acc + ((size_t)(t-d1)*B_ + arow)*H_ + i0;
          #pragma unroll
          for (int j = 0; j < 8; ++j){
            int c = (4*j + cofs) & 31;
            asm volatile("global_load_dwordx4 %0, %1, off sc0 sc1"
                         : "=v"(a1[2*j])   : "v"(s1 + c*8));
            asm volatile("global_load_dwordx4 %0, %1, off sc0 sc1"
                         : "=v"(a1[2*j+1]) : "v"(s1 + c*8 + 4));
          }
        }
        asm volatile("s_waitcnt vmcnt(0)" ::: "memory");
        __builtin_amdgcn_sched_barrier(0);
        #pragma unroll
        for (int j = 0; j < 8; ++j){
          int c = (4*j + cofs) & 31;
          f16x8 hh;
          #pragma unroll
          for (int e = 0; e < 8; ++e){
            float x = a0[2*j + (e>>2)][e & 3];
            float ex = __expf(2.0f * x);
            float hv = 1.0f - __fdividef(2.0f, ex + 1.0f);
            hh[e] = (_Float16)hv;
          }
          int byte = (arow*512 + c*16) ^ ((arow & 7) << 4);
          *(f16x8*)(ldsA0 + byte) = hh;
        }
        if (do1){
          #pragma unroll
          for (int j = 0; j < 8; ++j){
            int c = (4*j + cofs) & 31;
            f16x8 hh;
            #pragma unroll
            for (int e = 0; e < 8; ++e){
              float x = a1[2*j + (e>>2)][e & 3];
              float ex = __expf(2.0f * x);
              float hv = 1.0f - __fdividef(2.0f, ex + 1.0f);
              hh[e] = (_Float16)hv;
            }
            int byte = (arow*512 + c*16) ^ ((arow & 7) << 4);
            *(f16x8*)(ldsA1 + byte) = hh;
          }
        }
      }
      __syncthreads();

      // ---- MFMA: [64 x 512] total K (two 256 halves from different delays) ----
      f32x4 accr[4][2];
      #pragma unroll
      for (int a=0;a<4;++a){ accr[a][0]=(f32x4){0.f,0.f,0.f,0.f}; accr[a][1]=(f32x4){0.f,0.f,0.f,0.f}; }
      #pragma unroll 1
      for (int kk = 0; kk < 8; ++kk){
        int kb = (kk*32 + lkg*8) * 2;
        f16x8 afr[4];
        #pragma unroll
        for (int mt = 0; mt < 4; ++mt){
          int row = mt*16 + lr;
          afr[mt] = *(const f16x8*)(ldsA0 + ((row*512 + kb) ^ ((row & 7) << 4)));
        }
        #pragma unroll
        for (int nj = 0; nj < 2; ++nj){
          int ho = w*32 + nj*16 + lr;
          f16x8 bfr = *(const f16x8*)(ldsB0 + ((ho*512 + kb) ^ ((ho & 7) << 4)));
          #pragma unroll
          for (int mt = 0; mt < 4; ++mt)
            accr[mt][nj] = __builtin_amdgcn_mfma_f32_16x16x32_f16(afr[mt], bfr, accr[mt][nj],0,0,0);
        }
      }
      if (do1){
        #pragma unroll 1
        for (int kk = 0; kk < 8; ++kk){
          int kb = (kk*32 + lkg*8) * 2;
          f16x8 afr[4];
          #pragma unroll
          for (int mt = 0; mt < 4; ++mt){
            int row = mt*16 + lr;
            afr[mt] = *(const f16x8*)(ldsA1 + ((row*512 + kb) ^ ((row & 7) << 4)));
          }
          #pragma unroll
          for (int nj = 0; nj < 2; ++nj)
            #pragma unroll
            for (int mt = 0; mt < 4; ++mt)
              accr[mt][nj] = __builtin_amdgcn_mfma_f32_16x16x32_f16(afr[mt], bfr1[nj][kk], accr[mt][nj],0,0,0);
        }
      }

      // ---- scatter: ONE atomicAdd per element for both delays ----
      float* dst = acc + (size_t)t*B_*H_ + n*128;
      #pragma unroll
      for (int mt=0; mt<4; ++mt)
        #pragma unroll
        for (int nj=0; nj<2; ++nj){
          int ho = w*32 + nj*16 + lr;
          #pragma unroll
          for (int r2=0;r2<4;++r2){
            int b = mt*16 + (l>>4)*4 + r2;
            atomicAdd(dst + (size_t)b*H_ + ho, accr[mt][nj][r2] * CM_INV);
          }
        }
    }

    // ---- publish: my adds globally visible, then count step t done ----
    asm volatile("s_waitcnt vmcnt(0)" ::: "memory");
    __syncthreads();
    if (tid == 0)
      __hip_atomic_fetch_add(ctr + t, 1, __ATOMIC_RELAXED, __HIP_MEMORY_SCOPE_AGENT);
  }
}

// ---------- y[b][o] = (acc[255] - aff[255])[b][:] . we[o][:] + be[o] (f32) ----------
__global__ __launch_bounds__(256) void k_out(const float* __restrict__ acc255,
    const float* __restrict__ aff_last, const float* __restrict__ we,
    const float* __restrict__ be, float* __restrict__ y){
  int idx = blockIdx.x*256 + threadIdx.x;
  int b = idx >> 8, o = idx & 255;
  const float4* pa = (const float4*)(acc255 + (size_t)b*H_);
  const float4* pf = (const float4*)(aff_last + (size_t)b*H_);
  const float4* wb = (const float4*)(we + (size_t)o*H_);
  float s = 0.f;
  #pragma unroll 8
  for (int i2 = 0; i2 < H_/4; ++i2){
    float4 p = pa[i2], f = pf[i2], q = wb[i2];
    s += (p.x-f.x)*q.x + (p.y-f.y)*q.y + (p.z-f.z)*q.z + (p.w-f.w)*q.w;
  }
  y[idx] = s + be[o];
}

extern "C" void kernel_launch(void* const* d_in, const int* in_sizes, int n_in,
                              void* d_out, int out_size, void* d_ws, size_t ws_size,
                              hipStream_t stream){
  (void)in_sizes; (void)n_in; (void)out_size; (void)ws_size;
  const float* x   = (const float*)d_in[0];
  const float* wa  = (const float*)d_in[1];
  const float* ba  = (const float*)d_in[2];
  const float* lat = (const float*)d_in[3];
  const float* tau = (const float*)d_in[4];
  const float* we  = (const float*)d_in[5];
  const float* be  = (const float*)d_in[6];
  float* y = (float*)d_out;

  char* ws = (char*)d_ws;
  size_t cur = 0;
  auto alloc = [&](size_t sz) -> void* {
    void* p = ws + cur;
    cur += (sz + 255) & ~(size_t)255;
    return p;
  };
  int*      ctr      = (int*)     alloc(4096);                 // per-step completion counters
  float*    acc      = (float*)   alloc((size_t)T_*B_*H_*4);   // 33.5 MB preact accumulators
  float*    aff_last = (float*)   alloc((size_t)B_*H_*4);
  u16*      xhi      = (u16*)     alloc((size_t)B_*T_*I_*2);
  u16*      xlo      = (u16*)     alloc((size_t)B_*T_*I_*2);
  u16*      wahi     = (u16*)     alloc((size_t)H_*I_*2);
  u16*      walo     = (u16*)     alloc((size_t)H_*I_*2);
  _Float16* cmf      = (_Float16*)alloc((size_t)D_*H_*H_*2);

  // only the counters need zeroing (acc is fully initialized by k_aff)
  hipMemsetAsync(ctr, 0, 4096, stream);

  k_split<<<(B_*T_*I_+255)/256, 256, 0, stream>>>(x, xhi, xlo, B_*T_*I_);
  k_split<<<(H_*I_+255)/256,   256, 0, stream>>>(wa, wahi, walo, H_*I_);
  k_prep_cm<<<(D_*H_*H_+255)/256, 256, 0, stream>>>(tau, lat, cmf);
  k_aff<<<1024, 256, 0, stream>>>(xhi, xlo, wahi, walo, ba, acc, aff_last);
  k_rec<<<NWG, 256, 0, stream>>>(cmf, acc, ctr);
  k_out<<<(B_*O_+255)/256, 256, 0, stream>>>(acc + (size_t)(T_-1)*B_*H_, aff_last, we, be, y);
}

// Round 8
// 2745.926 us; speedup vs baseline: 1.1924x; 1.1924x over previous
//
#include <hip/hip_runtime.h>
#include <hip/hip_bf16.h>

typedef unsigned short u16;
typedef unsigned int u32;
typedef __bf16 bf16x8 __attribute__((ext_vector_type(8)));
typedef _Float16 f16x8 __attribute__((ext_vector_type(8)));
typedef float f32x4 __attribute__((ext_vector_type(4)));

#define B_ 64
#define T_ 256
#define I_ 256
#define H_ 512
#define O_ 256
#define D_ 16
#define NWG 128
#define CM_SCALE 64.0f
#define CM_INV   0.015625f

__device__ __forceinline__ bf16x8 ld_bf8(const u16* p){
  uint4 u = *(const uint4*)p;
  return __builtin_bit_cast(bf16x8, u);
}

// ---------- elementwise prep: f32 -> bf16 hi/lo split (afferent GEMM inputs) ----------
__global__ __launch_bounds__(256) void k_split(const float* __restrict__ src,
    u16* __restrict__ hi, u16* __restrict__ lo, int n){
  int i = blockIdx.x*256 + threadIdx.x;
  if (i >= n) return;
  float v = src[i];
  __bf16 h = (__bf16)v;
  __bf16 l = (__bf16)(v - (float)h);
  hi[i] = __builtin_bit_cast(u16, h);
  lo[i] = __builtin_bit_cast(u16, l);
}

// ---------- cm[d][ho][i] = relu(0.125 - |d - clip(tau,1,16)|/64) * lateral, f16 scaled x64 ----------
__global__ __launch_bounds__(256) void k_prep_cm(const float* __restrict__ tau,
    const float* __restrict__ lat, _Float16* __restrict__ cmf){
  int idx = blockIdx.x*256 + threadIdx.x;
  if (idx >= D_*H_*H_) return;
  int d = idx / (H_*H_) + 1;      // 1..16
  int r = idx % (H_*H_);
  float tc = fminf(fmaxf(tau[r], 1.0f), (float)D_);
  float cr = fmaxf(0.0f, 0.125f - fabsf((float)d - tc) * 0.015625f);
  cmf[idx] = (_Float16)(cr * lat[r] * CM_SCALE);
}

// ---------- afferent: acc[t][b][ho] = x[b][t][:] . wa[ho][:] + ba[ho] (3-MFMA bf16 split) ----------
__global__ __launch_bounds__(256) void k_aff(const u16* __restrict__ xhi,
    const u16* __restrict__ xlo, const u16* __restrict__ wahi,
    const u16* __restrict__ walo, const float* __restrict__ ba,
    float* __restrict__ acc, float* __restrict__ aff_last){
  int g = blockIdx.x;            // 1024 blocks
  int mg = g >> 2, ng = g & 3;   // 64-row m-group, 128-col n-group
  int tid = threadIdx.x;
  int w = tid >> 6, l = tid & 63;
  int lr = l & 15, lk8 = (l >> 4) * 8;
  f32x4 accr[4][2];
  #pragma unroll
  for (int a=0;a<4;++a){ accr[a][0]=(f32x4){0.f,0.f,0.f,0.f}; accr[a][1]=(f32x4){0.f,0.f,0.f,0.f}; }
  #pragma unroll 1
  for (int kk = 0; kk < 8; ++kk){
    int i = kk*32 + lk8;
    bf16x8 ahi[4], alo[4];
    #pragma unroll
    for (int mt = 0; mt < 4; ++mt){
      int r = mg*64 + mt*16 + lr;      // r = t*64 + b
      int t = r >> 6, b = r & 63;
      size_t off = ((size_t)b*T_ + t)*I_ + i;
      ahi[mt] = ld_bf8(xhi + off);
      alo[mt] = ld_bf8(xlo + off);
    }
    #pragma unroll
    for (int nj = 0; nj < 2; ++nj){
      int ho = ng*128 + w*32 + nj*16 + lr;
      bf16x8 bhi = ld_bf8(wahi + (size_t)ho*I_ + i);
      bf16x8 blo = ld_bf8(walo + (size_t)ho*I_ + i);
      #pragma unroll
      for (int mt = 0; mt < 4; ++mt){
        accr[mt][nj] = __builtin_amdgcn_mfma_f32_16x16x32_bf16(ahi[mt], bhi, accr[mt][nj],0,0,0);
        accr[mt][nj] = __builtin_amdgcn_mfma_f32_16x16x32_bf16(alo[mt], bhi, accr[mt][nj],0,0,0);
        accr[mt][nj] = __builtin_amdgcn_mfma_f32_16x16x32_bf16(ahi[mt], blo, accr[mt][nj],0,0,0);
      }
    }
  }
  #pragma unroll
  for (int mt=0; mt<4; ++mt)
    #pragma unroll
    for (int nj=0; nj<2; ++nj){
      int ho = ng*128 + w*32 + nj*16 + lr;
      float bias = ba[ho];
      #pragma unroll
      for (int r2=0;r2<4;++r2){
        int r = mg*64 + mt*16 + (l>>4)*4 + r2;   // r = t*64 + b
        float v = accr[mt][nj][r2] + bias;
        acc[(size_t)r*H_ + ho] = v;
        if ((r >> 6) == T_-1) aff_last[(size_t)(r & 63)*H_ + ho] = v;
      }
    }
}

// ---------- persistent recurrence: gather + software-pipelined A-load ----------
// WG g: n = g&3 (128-col out block), k = g>>2: d = (k>>1)+1, i0 = (k&1)*256 (K-slice).
// Per step: [drain pre-issued A-loads] -> tanh/pack -> B1 -> MFMA -> atomics ->
// B2(drain) -> publish ctr[t] -> poll ctr[t+1-d] -> issue A-loads for t+1.
// d>=2 WGs' poll returns instantly (slack), so their load latency hides under the
// d=1 critical chain; the tick collapses to the d=1 serial path.
__global__ __launch_bounds__(256,1) void k_rec(const _Float16* __restrict__ cmf,
    float* __restrict__ acc, int* __restrict__ ctr){
  __shared__ char lds[131072];   // [0,64K): cm swz; [64K,96K): A buf0; [96K,128K): A buf1
  char* ldsB = lds;
  const int g = blockIdx.x;
  const int n = g & 3;
  const int k = g >> 2;
  const int d = (k >> 1) + 1;
  const int i0 = (k & 1) * 256;
  const int tid = threadIdx.x;
  const int w = tid >> 6, l = tid & 63;
  const int lr = l & 15, lkg = l >> 4;

  // stage cm slice into LDS (once) — identical to R6
  for (int it = tid; it < 4096; it += 256){
    int ho = it >> 5;
    int c8 = (it & 31) * 8;
    f16x8 v = *(const f16x8*)(cmf + (((size_t)(d-1)*H_ + n*128 + ho)*H_ + i0 + c8));
    int byte = (ho*512 + c8*2) ^ ((ho & 7) << 4);
    *(f16x8*)(ldsB + byte) = v;
  }
  __syncthreads();

  const int arow = tid >> 2;           // pack: batch row this thread handles
  const int q    = tid & 3;
  const int cofs = q + ((arow & 1) << 2);  // conflict-free write slots (R6)

  f32x4 arr[16];                       // pipelined A-slab regs (live across back-edge)

  for (int t = 0; t < T_; ++t){
    if (t >= d){
      // ---- A-loads for this step were issued at the previous tail: drain ----
      asm volatile("s_waitcnt vmcnt(0)" ::: "memory");
      __builtin_amdgcn_sched_barrier(0);
      char* ldsA = lds + 65536 + (t & 1)*32768;
      // ---- tanh, pack f16 into ldsA (identical math/mapping to R6) ----
      #pragma unroll
      for (int j = 0; j < 8; ++j){
        int c = (4*j + cofs) & 31;
        f16x8 hh;
        #pragma unroll
        for (int e = 0; e < 8; ++e){
          float x = arr[2*j + (e>>2)][e & 3];
          float ex = __expf(2.0f * x);
          float hv = 1.0f - __fdividef(2.0f, ex + 1.0f);
          hh[e] = (_Float16)hv;
        }
        int byte = (arow*512 + c*16) ^ ((arow & 7) << 4);
        *(f16x8*)(ldsA + byte) = hh;
      }
      __syncthreads();   // B1: packs visible

      // ---- MFMA: [64 x 256] x cm^T [128 x 256] (identical to R6) ----
      f32x4 accr[4][2];
      #pragma unroll
      for (int a=0;a<4;++a){ accr[a][0]=(f32x4){0.f,0.f,0.f,0.f}; accr[a][1]=(f32x4){0.f,0.f,0.f,0.f}; }
      #pragma unroll 1
      for (int kk = 0; kk < 8; ++kk){
        int kb = (kk*32 + lkg*8) * 2;
        f16x8 afr[4];
        #pragma unroll
        for (int mt = 0; mt < 4; ++mt){
          int row = mt*16 + lr;
          afr[mt] = *(const f16x8*)(ldsA + ((row*512 + kb) ^ ((row & 7) << 4)));
        }
        #pragma unroll
        for (int nj = 0; nj < 2; ++nj){
          int ho = w*32 + nj*16 + lr;
          f16x8 bfr = *(const f16x8*)(ldsB + ((ho*512 + kb) ^ ((ho & 7) << 4)));
          #pragma unroll
          for (int mt = 0; mt < 4; ++mt)
            accr[mt][nj] = __builtin_amdgcn_mfma_f32_16x16x32_f16(afr[mt], bfr, accr[mt][nj],0,0,0);
        }
      }

      // ---- scatter: atomicAdd into acc[t] (identical to R6) ----
      float* dst = acc + (size_t)t*B_*H_ + n*128;
      #pragma unroll
      for (int mt=0; mt<4; ++mt)
        #pragma unroll
        for (int nj=0; nj<2; ++nj){
          int ho = w*32 + nj*16 + lr;
          #pragma unroll
          for (int r2=0;r2<4;++r2){
            int b = mt*16 + (l>>4)*4 + r2;
            atomicAdd(dst + (size_t)b*H_ + ho, accr[mt][nj][r2] * CM_INV);
          }
        }
    }

    // ---- B2: drain atomics (all waves), then publish ctr[t] ----
    asm volatile("s_waitcnt vmcnt(0)" ::: "memory");
    __syncthreads();
    if (tid == 0)
      __hip_atomic_fetch_add(ctr + t, 1, __ATOMIC_RELAXED, __HIP_MEMORY_SCOPE_AGENT);

    // ---- tail: poll dependency for step t+1, then issue its A-loads ----
    if (t+1 < T_ && t+1 >= d){
      if (tid == 0){
        int needed = t + 1 - d;        // acc[needed] must be complete
        while (__hip_atomic_load(ctr + needed, __ATOMIC_RELAXED, __HIP_MEMORY_SCOPE_AGENT) < NWG)
          __builtin_amdgcn_s_sleep(1);
      }
      __syncthreads();   // B3: dependency satisfied for all threads
      const float* srow = acc + ((size_t)(t+1-d)*B_ + arow)*H_ + i0;
      #pragma unroll
      for (int j = 0; j < 8; ++j){
        int c = (4*j + cofs) & 31;
        asm volatile("global_load_dwordx4 %0, %1, off sc0 sc1"
                     : "=v"(arr[2*j])   : "v"(srow + c*8));
        asm volatile("global_load_dwordx4 %0, %1, off sc0 sc1"
                     : "=v"(arr[2*j+1]) : "v"(srow + c*8 + 4));
      }
    }
  }
}

// ---------- y[b][o] = (acc[255] - aff[255])[b][:] . we[o][:] + be[o] (f32) ----------
__global__ __launch_bounds__(256) void k_out(const float* __restrict__ acc255,
    const float* __restrict__ aff_last, const float* __restrict__ we,
    const float* __restrict__ be, float* __restrict__ y){
  int idx = blockIdx.x*256 + threadIdx.x;
  int b = idx >> 8, o = idx & 255;
  const float4* pa = (const float4*)(acc255 + (size_t)b*H_);
  const float4* pf = (const float4*)(aff_last + (size_t)b*H_);
  const float4* wb = (const float4*)(we + (size_t)o*H_);
  float s = 0.f;
  #pragma unroll 8
  for (int i2 = 0; i2 < H_/4; ++i2){
    float4 p = pa[i2], f = pf[i2], q = wb[i2];
    s += (p.x-f.x)*q.x + (p.y-f.y)*q.y + (p.z-f.z)*q.z + (p.w-f.w)*q.w;
  }
  y[idx] = s + be[o];
}

extern "C" void kernel_launch(void* const* d_in, const int* in_sizes, int n_in,
                              void* d_out, int out_size, void* d_ws, size_t ws_size,
                              hipStream_t stream){
  (void)in_sizes; (void)n_in; (void)out_size; (void)ws_size;
  const float* x   = (const float*)d_in[0];
  const float* wa  = (const float*)d_in[1];
  const float* ba  = (const float*)d_in[2];
  const float* lat = (const float*)d_in[3];
  const float* tau = (const float*)d_in[4];
  const float* we  = (const float*)d_in[5];
  const float* be  = (const float*)d_in[6];
  float* y = (float*)d_out;

  char* ws = (char*)d_ws;
  size_t cur = 0;
  auto alloc = [&](size_t sz) -> void* {
    void* p = ws + cur;
    cur += (sz + 255) & ~(size_t)255;
    return p;
  };
  int*      ctr      = (int*)     alloc(4096);                 // per-step completion counters
  float*    acc      = (float*)   alloc((size_t)T_*B_*H_*4);   // 33.5 MB preact accumulators
  float*    aff_last = (float*)   alloc((size_t)B_*H_*4);
  u16*      xhi      = (u16*)     alloc((size_t)B_*T_*I_*2);
  u16*      xlo      = (u16*)     alloc((size_t)B_*T_*I_*2);
  u16*      wahi     = (u16*)     alloc((size_t)H_*I_*2);
  u16*      walo     = (u16*)     alloc((size_t)H_*I_*2);
  _Float16* cmf      = (_Float16*)alloc((size_t)D_*H_*H_*2);

  // only the counters need zeroing (acc is fully initialized by k_aff)
  hipMemsetAsync(ctr, 0, 4096, stream);

  k_split<<<(B_*T_*I_+255)/256, 256, 0, stream>>>(x, xhi, xlo, B_*T_*I_);
  k_split<<<(H_*I_+255)/256,   256, 0, stream>>>(wa, wahi, walo, H_*I_);
  k_prep_cm<<<(D_*H_*H_+255)/256, 256, 0, stream>>>(tau, lat, cmf);
  k_aff<<<1024, 256, 0, stream>>>(xhi, xlo, wahi, walo, ba, acc, aff_last);
  k_rec<<<NWG, 256, 0, stream>>>(cmf, acc, ctr);
  k_out<<<(B_*O_+255)/256, 256, 0, stream>>>(acc + (size_t)(T_-1)*B_*H_, aff_last, we, be, y);
}